// Round 13
// baseline (258.856 us; speedup 1.0000x reference)
//
#include <hip/hip_runtime.h>
#include <hip/hip_bf16.h>
#include <math.h>

#define EMBED   768
#define NHEADS  12
#define HD      64
#define HIDDEN  3072
#define SEQ     2048
#define BATCH   2
#define ROWS    (BATCH*SEQ)   // 4096

// exp(s/8) == exp2(s * 0.125*log2(e)); folded into Q at qkv-GEMM epilogue.
#define QSCALE  0.1803368801111204f

typedef __bf16 bf16_t;
typedef __attribute__((ext_vector_type(8))) __bf16 bf16x8;
typedef __attribute__((ext_vector_type(4))) __bf16 bf16x4;
typedef __attribute__((ext_vector_type(4))) float f32x4;

static __device__ __forceinline__ f32x4 mfma16(bf16x8 a, bf16x8 b, f32x4 c) {
  return __builtin_amdgcn_mfma_f32_16x16x32_bf16(a, b, c, 0, 0, 0);
}

// exp2 as a single v_exp_f32 WITH compiler-managed trans-op hazards.
#if defined(__HIP_DEVICE_COMPILE__) && __has_builtin(__builtin_amdgcn_exp2f)
static __device__ __forceinline__ float fast_exp2(float x) {
  return __builtin_amdgcn_exp2f(x);
}
#else
static __device__ __forceinline__ float fast_exp2(float x) { return exp2f(x); }
#endif

#if defined(__HIP_DEVICE_COMPILE__) && __has_builtin(__builtin_amdgcn_rcpf)
static __device__ __forceinline__ float fast_rcp(float x) {
  return __builtin_amdgcn_rcpf(x);
}
#else
static __device__ __forceinline__ float fast_rcp(float x) { return 1.0f / x; }
#endif

// async global->LDS, 16B per lane. LDS dest = wave-uniform base + lane*16.
typedef __attribute__((address_space(1))) const void gas_void;
typedef __attribute__((address_space(3))) void las_void;
static __device__ __forceinline__ void gll16(const void* g, void* l) {
  __builtin_amdgcn_global_load_lds((gas_void*)g, (las_void*)l, 16, 0, 0);
}

// ---------------------------------------------------------------------------
// Prep: all 4 weight transposes (fp32 [R,C] -> bf16 [C,R]) + LN1, ONE launch.
// ---------------------------------------------------------------------------
__global__ __launch_bounds__(256) void prep_kernel(
    const float* __restrict__ w0, bf16_t* __restrict__ o0,   // qkv  768x2304
    const float* __restrict__ w1, bf16_t* __restrict__ o1,   // proj 768x768
    const float* __restrict__ w2, bf16_t* __restrict__ o2,   // fc1  768x3072
    const float* __restrict__ w3, bf16_t* __restrict__ o3,   // fc2  3072x768
    const float* __restrict__ x,  const float* __restrict__ g,
    const float* __restrict__ bt, bf16_t* __restrict__ lnout)
{
  __shared__ float tile[32][33];
  __shared__ float red[8];
  int lin = blockIdx.x;
  if (lin < 6912) {
    const float* in; bf16_t* out; int R, C, bx, by;
    if (lin < 1728)      { in = w0; out = o0; R = 768;  C = 2304; bx = lin % 72; by = lin / 72; }
    else if (lin < 2304) { in = w1; out = o1; R = 768;  C = 768;  lin -= 1728; bx = lin % 24; by = lin / 24; }
    else if (lin < 4608) { in = w2; out = o2; R = 768;  C = 3072; lin -= 2304; bx = lin % 96; by = lin / 96; }
    else                 { in = w3; out = o3; R = 3072; C = 768;  lin -= 4608; bx = lin % 24; by = lin / 24; }
    int c0 = bx * 32, r0 = by * 32;
    int tx = threadIdx.x & 31, ty = threadIdx.x >> 5;
    #pragma unroll
    for (int p = 0; p < 4; ++p) {
      int r = ty + p * 8;
      tile[r][tx] = in[(size_t)(r0 + r) * C + c0 + tx];
    }
    __syncthreads();
    #pragma unroll
    for (int p = 0; p < 4; ++p) {
      int cc = ty + p * 8;
      out[(size_t)(c0 + cc) * R + r0 + tx] = (bf16_t)tile[tx][cc];
    }
    return;
  }
  // ---- LayerNorm rows ----
  int row = lin - 6912;
  int tid = threadIdx.x;
  const float* xr = x + (size_t)row * EMBED;
  float v0 = xr[tid], v1 = xr[tid + 256], v2 = xr[tid + 512];
  float s  = v0 + v1 + v2;
  float s2 = v0*v0 + v1*v1 + v2*v2;
  #pragma unroll
  for (int o = 32; o >= 1; o >>= 1) {
    s  += __shfl_xor(s,  o, 64);
    s2 += __shfl_xor(s2, o, 64);
  }
  int wave = tid >> 6, lane = tid & 63;
  if (lane == 0) { red[wave] = s; red[wave + 4] = s2; }
  __syncthreads();
  s  = red[0] + red[1] + red[2] + red[3];
  s2 = red[4] + red[5] + red[6] + red[7];
  float mu  = s * (1.0f / EMBED);
  float var = s2 * (1.0f / EMBED) - mu * mu;
  float rs  = rsqrtf(var + 1e-5f);
  bf16_t* orow = lnout + (size_t)row * EMBED;
  orow[tid]       = (bf16_t)((v0 - mu) * rs * g[tid]       + bt[tid]);
  orow[tid + 256] = (bf16_t)((v1 - mu) * rs * g[tid + 256] + bt[tid + 256]);
  orow[tid + 512] = (bf16_t)((v2 - mu) * rs * g[tid + 512] + bt[tid + 512]);
}

// ---------------------------------------------------------------------------
// Standalone LayerNorm (for ln2): one block per row. fp32 in -> bf16 out.
// ---------------------------------------------------------------------------
__global__ __launch_bounds__(256) void ln_kernel(
    const float* __restrict__ x, const float* __restrict__ g,
    const float* __restrict__ bt, bf16_t* __restrict__ out)
{
  int row = blockIdx.x;
  int tid = threadIdx.x;
  const float* xr = x + (size_t)row * EMBED;
  float v0 = xr[tid], v1 = xr[tid + 256], v2 = xr[tid + 512];
  float s  = v0 + v1 + v2;
  float s2 = v0*v0 + v1*v1 + v2*v2;
  #pragma unroll
  for (int o = 32; o >= 1; o >>= 1) {
    s  += __shfl_xor(s,  o, 64);
    s2 += __shfl_xor(s2, o, 64);
  }
  __shared__ float red[8];
  int wave = tid >> 6, lane = tid & 63;
  if (lane == 0) { red[wave] = s; red[wave + 4] = s2; }
  __syncthreads();
  s  = red[0] + red[1] + red[2] + red[3];
  s2 = red[4] + red[5] + red[6] + red[7];
  float mu  = s * (1.0f / EMBED);
  float var = s2 * (1.0f / EMBED) - mu * mu;
  float rs  = rsqrtf(var + 1e-5f);
  bf16_t* orow = out + (size_t)row * EMBED;
  orow[tid]       = (bf16_t)((v0 - mu) * rs * g[tid]       + bt[tid]);
  orow[tid + 256] = (bf16_t)((v1 - mu) * rs * g[tid + 256] + bt[tid + 256]);
  orow[tid + 512] = (bf16_t)((v2 - mu) * rs * g[tid + 512] + bt[tid + 512]);
}

// ---------------------------------------------------------------------------
// GEMM: out[M,N] = epi(A[M,K] @ WT[N,K]^T + bias [+res]).  BK=64.
// 128xBN tile, 1D grid, XCD-aware swizzle. global_load_lds staging, XOR-LDS.
// R13: k-loop is DOUBLE-BUFFERED with counted vmcnt ONLY for BN==64 (proj,
// fc2): dbuf LDS = 48KB keeps 3 blocks/CU there, and R6 measured fc2
// 43.4us dbuf vs 44.0-44.5 single. BN==128 stays single-buffered (R6: its
// 64KB dbuf dropped occupancy 5->2 blocks/CU, net loss).
// MODE 1: bf16 + tanh-GELU. MODE 2: fp32+residual. MODE 3 (qkv): bf16,
// n<768 scaled by QSCALE, n>=1536 (V) written transposed into vt.
// MODE 4 (fc2): split-K=2, fp32 atomicAdd (R10: dur invariant to A-locality
// decode; cost = staging BW + atomic tail. R5: SK=4/BN=128 atomics regress).
// ---------------------------------------------------------------------------
template<int MODE, int BN, int SK = 1>
__global__ __launch_bounds__(256) void gemm_kernel(
    const bf16_t* __restrict__ A, const bf16_t* __restrict__ WT,
    const float* __restrict__ bias, const float* __restrict__ res,
    void* __restrict__ outp, bf16_t* __restrict__ vt, int N, int K)
{
  constexpr int JT = BN / 32;              // n-subtiles per wave
  constexpr int NBUF = (BN == 64) ? 2 : 1; // dbuf only where LDS allows 3/CU
  __shared__ bf16_t As[NBUF * 128 * 64];
  __shared__ bf16_t Bs[NBUF * BN * 64];
  int tid = threadIdx.x;
  int lane = tid & 63, wave = tid >> 6;
  int l15 = lane & 15, quad = lane >> 4;
  int wm = wave >> 1, wn = wave & 1;

  int Nn = N / BN;
  int lin = blockIdx.x;
  int kslice = 0, k_lo = 0, k_hi = K;
  if (MODE == 4) {
    kslice = lin % SK; lin /= SK;
    k_lo = kslice * (K / SK); k_hi = k_lo + K / SK;
  }
  int bm = (lin & 7) + 8 * ((lin >> 3) / Nn);
  int bn = (lin >> 3) % Nn;
  int m0 = bm * 128, n0 = bn * BN;

  f32x4 acc[4][JT];
  #pragma unroll
  for (int i = 0; i < 4; ++i)
    #pragma unroll
    for (int j = 0; j < JT; ++j)
      acc[i][j] = (f32x4){0.f, 0.f, 0.f, 0.f};

  int grow = lane >> 3;                     // 0..7
  int gcol = ((lane & 7) ^ grow) * 8;       // logical chunk for phys slot
  const bf16_t* abase = A  + (size_t)(m0 + wave * 32 + grow) * K + gcol;
  const bf16_t* bbase = WT + (size_t)(n0 + wave * (BN / 4) + grow) * K + gcol;
  int swk = l15 & 7;

  if constexpr (NBUF == 2) {
    // ---- double-buffered k-loop (BN=64: 4 A-loads + 2 B-loads per wave) --
    auto stageg = [&](int k0, int buf) {
      bf16_t* asp = &As[buf * (128 * 64)];
      bf16_t* bsp = &Bs[buf * (BN * 64)];
      #pragma unroll
      for (int a = 0; a < 4; ++a)
        gll16(abase + (size_t)a * 8 * K + k0, &asp[(wave * 32 + a * 8) * 64]);
      #pragma unroll
      for (int a = 0; a < BN / 32; ++a)
        gll16(bbase + (size_t)a * 8 * K + k0, &bsp[(wave * (BN / 4) + a * 8) * 64]);
    };
    int nsteps = (k_hi - k_lo) / 64;
    stageg(k_lo, 0);
    for (int t = 0; t < nsteps; ++t) {
      if (t + 1 < nsteps) {
        stageg(k_lo + (t + 1) * 64, (t + 1) & 1);
        __asm__ volatile("s_waitcnt vmcnt(6)" ::: "memory");
      } else {
        __asm__ volatile("s_waitcnt vmcnt(0)" ::: "memory");
      }
      __builtin_amdgcn_s_barrier();        // current tile's loads all landed
      __builtin_amdgcn_sched_barrier(0);   // pin ds_reads below the barrier

      const bf16_t* asp = &As[(t & 1) * (128 * 64)];
      const bf16_t* bsp = &Bs[(t & 1) * (BN * 64)];
      #pragma unroll
      for (int g = 0; g < 2; ++g) {
        bf16x8 af[4], bfr[JT];
        #pragma unroll
        for (int i = 0; i < 4; ++i)
          af[i] = *(const bf16x8*)
              &asp[(wm * 64 + i * 16 + l15) * 64 + (((g * 4 + quad) ^ swk) * 8)];
        #pragma unroll
        for (int j = 0; j < JT; ++j)
          bfr[j] = *(const bf16x8*)
              &bsp[(wn * (BN / 2) + j * 16 + l15) * 64 + (((g * 4 + quad) ^ swk) * 8)];
        #pragma unroll
        for (int i = 0; i < 4; ++i)
          #pragma unroll
          for (int j = 0; j < JT; ++j)
            acc[i][j] = mfma16(af[i], bfr[j], acc[i][j]);
      }
      // this buffer's ds_reads complete before anyone overwrites it
      __asm__ volatile("s_waitcnt lgkmcnt(0)" ::: "memory");
      __builtin_amdgcn_s_barrier();
    }
  } else {
    // ---- single-buffered k-loop (BN=128: dbuf would halve occupancy) ----
    for (int k0 = k_lo; k0 < k_hi; k0 += 64) {
      #pragma unroll
      for (int a = 0; a < 4; ++a)
        gll16(abase + (size_t)a * 8 * K + k0, &As[(wave * 32 + a * 8) * 64]);
      #pragma unroll
      for (int a = 0; a < BN / 32; ++a)
        gll16(bbase + (size_t)a * 8 * K + k0, &Bs[(wave * (BN / 4) + a * 8) * 64]);
      __syncthreads();

      #pragma unroll
      for (int g = 0; g < 2; ++g) {
        bf16x8 af[4], bfr[JT];
        #pragma unroll
        for (int i = 0; i < 4; ++i)
          af[i] = *(const bf16x8*)
              &As[(wm * 64 + i * 16 + l15) * 64 + (((g * 4 + quad) ^ swk) * 8)];
        #pragma unroll
        for (int j = 0; j < JT; ++j)
          bfr[j] = *(const bf16x8*)
              &Bs[(wn * (BN / 2) + j * 16 + l15) * 64 + (((g * 4 + quad) ^ swk) * 8)];
        #pragma unroll
        for (int i = 0; i < 4; ++i)
          #pragma unroll
          for (int j = 0; j < JT; ++j)
            acc[i][j] = mfma16(af[i], bfr[j], acc[i][j]);
      }
      __syncthreads();
    }
  }

  #pragma unroll
  for (int i = 0; i < 4; ++i) {
    int mbase = m0 + wm * 64 + i * 16 + quad * 4;
    #pragma unroll
    for (int j = 0; j < JT; ++j) {
      int n = n0 + wn * (BN / 2) + j * 16 + l15;
      float bn_ = (MODE == 4 && kslice != 0) ? 0.f : bias[n];
      if (MODE == 3 && n >= 1536) {
        // V output -> vt[bh][d][l], packed 4 consecutive l per lane
        int dcol = n - 1536;
        int hh = dcol >> 6, dd = dcol & 63;
        int bsel = mbase >> 11, l = mbase & 2047;
        union { bf16_t b4[4]; uint2 u; } pk;
        #pragma unroll
        for (int r = 0; r < 4; ++r)
          pk.b4[r] = (bf16_t)(acc[i][j][r] + bn_);
        *(uint2*)&vt[(((size_t)bsel * NHEADS + hh) * HD + dd) * SEQ + l] = pk.u;
        continue;
      }
      #pragma unroll
      for (int r = 0; r < 4; ++r) {
        size_t idx = (size_t)(mbase + r) * N + n;
        float v = acc[i][j][r] + bn_;
        if (MODE == 1) {
          // tanh-GELU: v * e/(e+1), e = exp(2*0.79788456*(v+0.044715 v^3))
          float e = fast_exp2(fminf(v * (2.3020807f + 0.10293776f * v * v), 120.f));
          v = v * e * fast_rcp(e + 1.0f);
        }
        if (MODE == 3 && n < 768) v *= QSCALE;
        if (MODE == 2) {
          v += res[idx];
          ((float*)outp)[idx] = v;
        } else if (MODE == 4) {
          atomicAdd((float*)outp + idx, v);
        } else {
          ((bf16_t*)outp)[idx] = (bf16_t)v;
        }
      }
    }
  }
}

// ---------------------------------------------------------------------------
// Flash attention (R7/R8 body, measured best 43.7-45.2us — LOCKED).
// R9 (phase-batching) and R11 (deep prefetch + setprio) both regressed with
// a scratch-spill signature (WRITE_SIZE +10-18MB): the body sits exactly at
// the 84-VGPR/3-wave boundary; any restructure that widens live ranges
// spills and loses more than the schedule gains. R8's FETCH-collapse
// (53->10MB, dur flat) proved attn is NOT memory-bound; its floor is the
// per-pair issue chain at 3 waves/SIMD. Do not touch without a VGPR budget.
//   * XCD-grouped (b,h) mapping (R7): FETCH ~10MB.
//   * Pair-processed K=32 PV + ones-MFMA denominators (R3).
//   * V LDS 16B-half XOR swizzle; ring-3 wave-private bufs; guarded final
//     prefetch.
// ---------------------------------------------------------------------------
__global__ __launch_bounds__(256, 3) void attn_kernel(
    const bf16_t* __restrict__ qkv, const bf16_t* __restrict__ vt,
    bf16_t* __restrict__ attnout)
{
  // per wave: 3 bufs x (K 16x64 | V 64x16) = 12KB -> 48KB total
  __attribute__((aligned(16))) __shared__ bf16_t smem[4 * 3 * 2048];
  __shared__ float dsumf[4][64];

  // XCD-aware decode: xcd = blockIdx%8 owns bh in [xcd*3, xcd*3+3), all qt.
  int lin = blockIdx.x;
  int xcd = lin & 7;
  int idx = lin >> 3;               // 0..95
  int bh  = xcd * 3 + (idx >> 5);   // 0..23
  int qt  = idx & 31;
  int b = bh / NHEADS, h = bh % NHEADS;

  int tid = threadIdx.x;
  int wave = tid >> 6, lane = tid & 63;
  int l15 = lane & 15, quad = lane >> 4;
  int q0 = qt * 64;

  bf16_t* wbase = smem + wave * 3 * 2048;   // ring of 3: [K 1024 | V 1024]

  // Q B-frags (pre-scaled by QSCALE): n=q=l15, k=d=f*32+quad*8+j
  bf16x8 bq[4][2];
  #pragma unroll
  for (int qi = 0; qi < 4; ++qi) {
    const bf16_t* qrow = qkv + (size_t)(b * SEQ + q0 + qi * 16 + l15) * 2304
                             + h * HD + quad * 8;
    bq[qi][0] = *(const bf16x8*)qrow;
    bq[qi][1] = *(const bf16x8*)(qrow + 32);
  }
  // drain Q loads so in-loop vmcnt tracks only gll16 staging ops
  __asm__ volatile("s_waitcnt vmcnt(0)" ::: "memory");

  f32x4 accO[4][4];
  f32x4 accL[4];
  #pragma unroll
  for (int qi = 0; qi < 4; ++qi) {
    accL[qi] = (f32x4){0.f, 0.f, 0.f, 0.f};
    #pragma unroll
    for (int t2 = 0; t2 < 4; ++t2)
      accO[qi][t2] = (f32x4){0.f, 0.f, 0.f, 0.f};
  }

  // ones B-frag for denominator row-sum MFMA
  bf16x8 ones;
  #pragma unroll
  for (int r = 0; r < 8; ++r) ones[r] = (bf16_t)1.0f;

  // staging lane mappings (wave-private tiles, coalesced 16B/lane)
  int krow_l = lane >> 3;                      // 0..7
  int kchunk = ((lane & 7) ^ krow_l) * 8;      // XOR-swizzled phys chunk
  const bf16_t* ksrc0 = qkv + (size_t)(b * SEQ + wave * 16 + krow_l) * 2304
                            + 768 + h * HD + kchunk;
  int vrow_l = lane >> 1;                      // 0..31 (d rows)
  // 16B-half XOR swizzle: phys half = logical half ^ ((d>>2)&1)
  int vchunk = ((lane & 1) ^ ((vrow_l >> 2) & 1)) * 8;
  const bf16_t* vsrc0 = vt + ((size_t)bh * HD + vrow_l) * SEQ + wave * 16 + vchunk;

  constexpr int NIT = SEQ / 64;    // 32 tiles, 16 pairs

  // stage tile t into ring buffer t%3
  auto stage = [&](int t) {
    bf16_t* kb = wbase + (t % 3) * 2048;
    bf16_t* vb = kb + 1024;
    const bf16_t* ks = ksrc0 + (size_t)(t * 64) * 2304;
    const bf16_t* vs = vsrc0 + t * 64;
    #pragma unroll
    for (int p = 0; p < 2; ++p) {
      gll16(ks + (size_t)(p * 8) * 2304, kb + p * 512);
      gll16(vs + (size_t)(p * 32) * SEQ, vb + p * 512);
    }
  };

  // prologue: stage tiles 0,1
  stage(0);
  stage(1);

  // V read offset within a tile's 16-kv row (for B-frag slots j=0..3):
  // logical kv = quad*4+j -> phys = (half^((l15>>2)&1))*8 + (quad&1)*4 + j
  int vphys = (((quad >> 1) ^ ((l15 >> 2) & 1)) * 8) + (quad & 1) * 4;

  for (int p = 0; p < NIT / 2; ++p) {
    int ta = 2 * p, tb = 2 * p + 1;
    // wait for both tiles of this pair (prefetched one pair-compute ago)
    __asm__ volatile("s_waitcnt vmcnt(0)" ::: "memory");

    const bf16_t* kba = wbase + (ta % 3) * 2048;
    const bf16_t* vba = kba + 1024;
    const bf16_t* kbb = wbase + (tb % 3) * 2048;
    const bf16_t* vbb = kbb + 1024;

    // K A-frags: m=kv=l15, k=d=(f*4+quad)*8+j ; swizzle phys=c^(l15&7)
    bf16x8 aka[2], akb[2];
    #pragma unroll
    for (int f = 0; f < 2; ++f) {
      int koff = (((f * 4 + quad) ^ (l15 & 7)) * 8);
      aka[f] = *(const bf16x8*)&kba[l15 * 64 + koff];
      akb[f] = *(const bf16x8*)&kbb[l15 * 64 + koff];
    }

    // combined V B-frag (K=32): j 0..3 from tile a, 4..7 from tile b
    bf16x8 bv8[4];
    #pragma unroll
    for (int t2 = 0; t2 < 4; ++t2) {
      bf16x4 lo = *(const bf16x4*)&vba[(t2 * 16 + l15) * 16 + vphys];
      bf16x4 hi = *(const bf16x4*)&vbb[(t2 * 16 + l15) * 16 + vphys];
      bf16x8 c;
      #pragma unroll
      for (int r = 0; r < 4; ++r) { c[r] = lo[r]; c[r + 4] = hi[r]; }
      bv8[t2] = c;
    }

    // frags now issued; drain LDS reads, then overwrite-safe to prefetch
    __asm__ volatile("s_waitcnt lgkmcnt(0)" ::: "memory");
    if (p < NIT / 2 - 1) {
      stage(2 * p + 2);
      stage(2 * p + 3);
    }

    #pragma unroll
    for (int qi = 0; qi < 4; ++qi) {
      f32x4 sa = (f32x4){0.f, 0.f, 0.f, 0.f};
      sa = mfma16(aka[0], bq[qi][0], sa);   // S^T: (kv=quad*4+r, q=l15)
      sa = mfma16(aka[1], bq[qi][1], sa);
      f32x4 sb = (f32x4){0.f, 0.f, 0.f, 0.f};
      sb = mfma16(akb[0], bq[qi][0], sb);
      sb = mfma16(akb[1], bq[qi][1], sb);
      bf16x8 ap;
      #pragma unroll
      for (int r = 0; r < 4; ++r) {
        ap[r]     = (bf16_t)fast_exp2(sa[r]);
        ap[r + 4] = (bf16_t)fast_exp2(sb[r]);
      }
      // denominator row-sums on the matrix pipe
      accL[qi] = mfma16(ap, ones, accL[qi]);
      // S^T C-layout == K=32 A-frag layout of P: feed PV directly
      #pragma unroll
      for (int t2 = 0; t2 < 4; ++t2)
        accO[qi][t2] = mfma16(ap, bv8[t2], accO[qi][t2]);
    }
  }

  // publish denominators: accL C-layout: row q_sub=quad*4+r, col l15 (equal
  // across l15) -> lanes with l15==0 write 4 rows each
  if (l15 == 0) {
    #pragma unroll
    for (int qi = 0; qi < 4; ++qi)
      #pragma unroll
      for (int r = 0; r < 4; ++r)
        dsumf[wave][qi * 16 + quad * 4 + r] = accL[qi][r];
  }
  __syncthreads();   // waves done with private tiles; dsumf published

  float* slabf = (float*)smem;   // 4 slabs x 2048 f32 = 32 KB (ring region)

  for (int pass = 0; pass < 2; ++pass) {
    #pragma unroll
    for (int qi2 = 0; qi2 < 2; ++qi2) {
      int qi = pass * 2 + qi2;
      #pragma unroll
      for (int t2 = 0; t2 < 4; ++t2)
        #pragma unroll
        for (int r = 0; r < 4; ++r)
          slabf[wave * 2048 + (qi2 * 16 + quad * 4 + r) * 64 + t2 * 16 + l15]
              = accO[qi][t2][r];
    }
    __syncthreads();
    int row = tid >> 3;            // 0..31
    int d0 = (tid & 7) * 8;
    f32x4 o0 = (f32x4){0.f,0.f,0.f,0.f}, o1 = (f32x4){0.f,0.f,0.f,0.f};
    #pragma unroll
    for (int sw = 0; sw < 4; ++sw) {
      o0 += *(const f32x4*)&slabf[sw * 2048 + row * 64 + d0];
      o1 += *(const f32x4*)&slabf[sw * 2048 + row * 64 + d0 + 4];
    }
    int q_abs = pass * 32 + row;
    float den = dsumf[0][q_abs] + dsumf[1][q_abs] + dsumf[2][q_abs] + dsumf[3][q_abs];
    float inv = 1.0f / den;
    bf16_t ob[8];
    #pragma unroll
    for (int j = 0; j < 4; ++j) {
      ob[j]     = (bf16_t)(o0[j] * inv);
      ob[j + 4] = (bf16_t)(o1[j] * inv);
    }
    *(uint4*)&attnout[(size_t)(b * SEQ + q0 + q_abs) * EMBED + h * HD + d0]
        = *(const uint4*)ob;
    if (pass == 0) __syncthreads();
  }
}

// ---------------------------------------------------------------------------
extern "C" void kernel_launch(void* const* d_in, const int* in_sizes, int n_in,
                              void* d_out, int out_size, void* d_ws, size_t ws_size,
                              hipStream_t stream) {
  (void)in_sizes; (void)n_in; (void)out_size; (void)ws_size;
  const float* x      = (const float*)d_in[0];
  const float* ln1_g  = (const float*)d_in[1];
  const float* ln1_b  = (const float*)d_in[2];
  const float* qkv_w  = (const float*)d_in[3];
  const float* qkv_b  = (const float*)d_in[4];
  const float* proj_w = (const float*)d_in[5];
  const float* proj_b = (const float*)d_in[6];
  const float* ln2_g  = (const float*)d_in[7];
  const float* ln2_b  = (const float*)d_in[8];
  const float* fc1_w  = (const float*)d_in[9];
  const float* fc1_b  = (const float*)d_in[10];
  const float* fc2_w  = (const float*)d_in[11];
  const float* fc2_b  = (const float*)d_in[12];
  float* out = (float*)d_out;

  char* p = (char*)d_ws;
  bf16_t* wqkvT  = (bf16_t*)p; p += (size_t)2304 * 768 * 2;
  bf16_t* wprojT = (bf16_t*)p; p += (size_t)768 * 768 * 2;
  bf16_t* wfc1T  = (bf16_t*)p; p += (size_t)3072 * 768 * 2;
  bf16_t* wfc2T  = (bf16_t*)p; p += (size_t)768 * 3072 * 2;
  bf16_t* hbuf   = (bf16_t*)p; p += (size_t)ROWS * 768 * 2;
  bf16_t* qkv    = (bf16_t*)p;          // dead after attention
  bf16_t* hid    = (bf16_t*)p; p += (size_t)ROWS * 3072 * 2;  // aliases qkv
  bf16_t* vt     = (bf16_t*)p; p += (size_t)BATCH * NHEADS * HD * SEQ * 2;
  bf16_t* attno  = (bf16_t*)p; p += (size_t)ROWS * 768 * 2;

  // weight prep + LN1 (one launch; no static state allowed)
  prep_kernel<<<6912 + ROWS, 256, 0, stream>>>(
      qkv_w, wqkvT, proj_w, wprojT, fc1_w, wfc1T, fc2_w, wfc2T,
      x, ln1_g, ln1_b, hbuf);

  // attention sublayer (qkv GEMM writes V directly transposed into vt)
  gemm_kernel<3,128><<<32 * (2304/128), 256, 0, stream>>>(
      hbuf, wqkvT, qkv_b, nullptr, qkv, vt, 2304, 768);
  attn_kernel<<<768, 256, 0, stream>>>(qkv, vt, attno);
  gemm_kernel<2,64><<<32 * (768/64), 256, 0, stream>>>(
      attno, wprojT, proj_b, x, out, nullptr, 768, 768);

  // FFN sublayer
  ln_kernel<<<ROWS, 256, 0, stream>>>(out, ln2_g, ln2_b, hbuf);
  gemm_kernel<1,128><<<32 * (3072/128), 256, 0, stream>>>(
      hbuf, wfc1T, fc1_b, nullptr, hid, nullptr, 3072, 768);
  gemm_kernel<4,64,2><<<2 * 32 * (768/64), 256, 0, stream>>>(
      hid, wfc2T, fc2_b, nullptr, out, nullptr, 768, 3072);
}

// Round 14
// 250.924 us; speedup vs baseline: 1.0316x; 1.0316x over previous
//
#include <hip/hip_runtime.h>
#include <hip/hip_bf16.h>
#include <math.h>

#define EMBED   768
#define NHEADS  12
#define HD      64
#define HIDDEN  3072
#define SEQ     2048
#define BATCH   2
#define ROWS    (BATCH*SEQ)   // 4096

// exp(s/8) == exp2(s * 0.125*log2(e)); folded into Q at qkv-GEMM epilogue.
#define QSCALE  0.1803368801111204f

typedef __bf16 bf16_t;
typedef __attribute__((ext_vector_type(8))) __bf16 bf16x8;
typedef __attribute__((ext_vector_type(4))) __bf16 bf16x4;
typedef __attribute__((ext_vector_type(4))) float f32x4;

static __device__ __forceinline__ f32x4 mfma16(bf16x8 a, bf16x8 b, f32x4 c) {
  return __builtin_amdgcn_mfma_f32_16x16x32_bf16(a, b, c, 0, 0, 0);
}

// exp2 as a single v_exp_f32 WITH compiler-managed trans-op hazards.
#if defined(__HIP_DEVICE_COMPILE__) && __has_builtin(__builtin_amdgcn_exp2f)
static __device__ __forceinline__ float fast_exp2(float x) {
  return __builtin_amdgcn_exp2f(x);
}
#else
static __device__ __forceinline__ float fast_exp2(float x) { return exp2f(x); }
#endif

#if defined(__HIP_DEVICE_COMPILE__) && __has_builtin(__builtin_amdgcn_rcpf)
static __device__ __forceinline__ float fast_rcp(float x) {
  return __builtin_amdgcn_rcpf(x);
}
#else
static __device__ __forceinline__ float fast_rcp(float x) { return 1.0f / x; }
#endif

// async global->LDS, 16B per lane. LDS dest = wave-uniform base + lane*16.
typedef __attribute__((address_space(1))) const void gas_void;
typedef __attribute__((address_space(3))) void las_void;
static __device__ __forceinline__ void gll16(const void* g, void* l) {
  __builtin_amdgcn_global_load_lds((gas_void*)g, (las_void*)l, 16, 0, 0);
}

// ---------------------------------------------------------------------------
// Prep: all 4 weight transposes (fp32 [R,C] -> bf16 [C,R]) + LN1, ONE launch.
// ---------------------------------------------------------------------------
__global__ __launch_bounds__(256) void prep_kernel(
    const float* __restrict__ w0, bf16_t* __restrict__ o0,   // qkv  768x2304
    const float* __restrict__ w1, bf16_t* __restrict__ o1,   // proj 768x768
    const float* __restrict__ w2, bf16_t* __restrict__ o2,   // fc1  768x3072
    const float* __restrict__ w3, bf16_t* __restrict__ o3,   // fc2  3072x768
    const float* __restrict__ x,  const float* __restrict__ g,
    const float* __restrict__ bt, bf16_t* __restrict__ lnout)
{
  __shared__ float tile[32][33];
  __shared__ float red[8];
  int lin = blockIdx.x;
  if (lin < 6912) {
    const float* in; bf16_t* out; int R, C, bx, by;
    if (lin < 1728)      { in = w0; out = o0; R = 768;  C = 2304; bx = lin % 72; by = lin / 72; }
    else if (lin < 2304) { in = w1; out = o1; R = 768;  C = 768;  lin -= 1728; bx = lin % 24; by = lin / 24; }
    else if (lin < 4608) { in = w2; out = o2; R = 768;  C = 3072; lin -= 2304; bx = lin % 96; by = lin / 96; }
    else                 { in = w3; out = o3; R = 3072; C = 768;  lin -= 4608; bx = lin % 24; by = lin / 24; }
    int c0 = bx * 32, r0 = by * 32;
    int tx = threadIdx.x & 31, ty = threadIdx.x >> 5;
    #pragma unroll
    for (int p = 0; p < 4; ++p) {
      int r = ty + p * 8;
      tile[r][tx] = in[(size_t)(r0 + r) * C + c0 + tx];
    }
    __syncthreads();
    #pragma unroll
    for (int p = 0; p < 4; ++p) {
      int cc = ty + p * 8;
      out[(size_t)(c0 + cc) * R + r0 + tx] = (bf16_t)tile[tx][cc];
    }
    return;
  }
  // ---- LayerNorm rows ----
  int row = lin - 6912;
  int tid = threadIdx.x;
  const float* xr = x + (size_t)row * EMBED;
  float v0 = xr[tid], v1 = xr[tid + 256], v2 = xr[tid + 512];
  float s  = v0 + v1 + v2;
  float s2 = v0*v0 + v1*v1 + v2*v2;
  #pragma unroll
  for (int o = 32; o >= 1; o >>= 1) {
    s  += __shfl_xor(s,  o, 64);
    s2 += __shfl_xor(s2, o, 64);
  }
  int wave = tid >> 6, lane = tid & 63;
  if (lane == 0) { red[wave] = s; red[wave + 4] = s2; }
  __syncthreads();
  s  = red[0] + red[1] + red[2] + red[3];
  s2 = red[4] + red[5] + red[6] + red[7];
  float mu  = s * (1.0f / EMBED);
  float var = s2 * (1.0f / EMBED) - mu * mu;
  float rs  = rsqrtf(var + 1e-5f);
  bf16_t* orow = lnout + (size_t)row * EMBED;
  orow[tid]       = (bf16_t)((v0 - mu) * rs * g[tid]       + bt[tid]);
  orow[tid + 256] = (bf16_t)((v1 - mu) * rs * g[tid + 256] + bt[tid + 256]);
  orow[tid + 512] = (bf16_t)((v2 - mu) * rs * g[tid + 512] + bt[tid + 512]);
}

// ---------------------------------------------------------------------------
// Standalone LayerNorm (for ln2): one block per row. fp32 in -> bf16 out.
// ---------------------------------------------------------------------------
__global__ __launch_bounds__(256) void ln_kernel(
    const float* __restrict__ x, const float* __restrict__ g,
    const float* __restrict__ bt, bf16_t* __restrict__ out)
{
  int row = blockIdx.x;
  int tid = threadIdx.x;
  const float* xr = x + (size_t)row * EMBED;
  float v0 = xr[tid], v1 = xr[tid + 256], v2 = xr[tid + 512];
  float s  = v0 + v1 + v2;
  float s2 = v0*v0 + v1*v1 + v2*v2;
  #pragma unroll
  for (int o = 32; o >= 1; o >>= 1) {
    s  += __shfl_xor(s,  o, 64);
    s2 += __shfl_xor(s2, o, 64);
  }
  __shared__ float red[8];
  int wave = tid >> 6, lane = tid & 63;
  if (lane == 0) { red[wave] = s; red[wave + 4] = s2; }
  __syncthreads();
  s  = red[0] + red[1] + red[2] + red[3];
  s2 = red[4] + red[5] + red[6] + red[7];
  float mu  = s * (1.0f / EMBED);
  float var = s2 * (1.0f / EMBED) - mu * mu;
  float rs  = rsqrtf(var + 1e-5f);
  bf16_t* orow = out + (size_t)row * EMBED;
  orow[tid]       = (bf16_t)((v0 - mu) * rs * g[tid]       + bt[tid]);
  orow[tid + 256] = (bf16_t)((v1 - mu) * rs * g[tid + 256] + bt[tid + 256]);
  orow[tid + 512] = (bf16_t)((v2 - mu) * rs * g[tid + 512] + bt[tid + 512]);
}

// ---------------------------------------------------------------------------
// GEMM: out[M,N] = epi(A[M,K] @ WT[N,K]^T + bias [+res]).
// 128xBN tile, 1D grid, XCD-aware swizzle. global_load_lds staging, XOR-LDS.
// R14: BK = 128 for BN==64 (proj, fc2), 64 for BN==128 (qkv, fc1).
// Evidence chain: fc2's per-k-step cost ~4400cy is NOT HBM (0.7TB/s), NOT
// L2 BW (29% of ceiling), NOT miss latency (R10: FETCH-invariant), NOT the
// vmem drain alone (R6/R13: counted-vmcnt dbuf with SAME barrier count was
// ~neutral). It's the per-step barrier/resync tail. BK=128 halves the step
// count at constant bytes: fc2 24->12 steps, proj 12->6. LDS at BN=64/BK=128
// = 48KB keeps 3 blocks/CU (unlike m132's BK=128@BN=128 which halved
// occupancy). BK=128 staging: 4 rows/gll16 (lane>>4), 16-chunk XOR swizzle
// chunk^(row&15); frag reads 2-way bank aliasing = free.
// MODE 1: bf16 + tanh-GELU. MODE 2: fp32+residual. MODE 3 (qkv): bf16,
// n<768 scaled by QSCALE, n>=1536 (V) written transposed into vt.
// MODE 4 (fc2): split-K=2, fp32 atomicAdd (R5: SK=4/BN=128 atomics regress).
// ---------------------------------------------------------------------------
template<int MODE, int BN, int SK = 1>
__global__ __launch_bounds__(256) void gemm_kernel(
    const bf16_t* __restrict__ A, const bf16_t* __restrict__ WT,
    const float* __restrict__ bias, const float* __restrict__ res,
    void* __restrict__ outp, bf16_t* __restrict__ vt, int N, int K)
{
  constexpr int JT = BN / 32;              // n-subtiles per wave
  constexpr int BK = (BN == 64) ? 128 : 64;
  __shared__ bf16_t As[128 * BK];
  __shared__ bf16_t Bs[BN * BK];
  int tid = threadIdx.x;
  int lane = tid & 63, wave = tid >> 6;
  int l15 = lane & 15, quad = lane >> 4;
  int wm = wave >> 1, wn = wave & 1;

  int Nn = N / BN;
  int lin = blockIdx.x;
  int kslice = 0, k_lo = 0, k_hi = K;
  if (MODE == 4) {
    kslice = lin % SK; lin /= SK;
    k_lo = kslice * (K / SK); k_hi = k_lo + K / SK;
  }
  int bm = (lin & 7) + 8 * ((lin >> 3) / Nn);
  int bn = (lin >> 3) % Nn;
  int m0 = bm * 128, n0 = bn * BN;

  f32x4 acc[4][JT];
  #pragma unroll
  for (int i = 0; i < 4; ++i)
    #pragma unroll
    for (int j = 0; j < JT; ++j)
      acc[i][j] = (f32x4){0.f, 0.f, 0.f, 0.f};

  if constexpr (BK == 128) {
    // ---- BK=128 k-loop: half the barrier-drain count, same bytes --------
    int rowl = lane >> 4;                   // 0..3 rows per gll16
    int c16  = lane & 15;                   // 16B chunk slot within 256B row
    for (int k0 = k_lo; k0 < k_hi; k0 += 128) {
      // A: 128 rows x 128 cols; wave stages rows wave*32 .. +31 (8 gll16)
      #pragma unroll
      for (int a = 0; a < 8; ++a) {
        int r0 = wave * 32 + a * 4;
        int row = r0 + rowl;
        int col = ((c16 ^ ((a * 4 + rowl) & 15)) * 8);   // pre-swizzled src
        gll16(A + (size_t)(m0 + row) * K + k0 + col, &As[r0 * 128]);
      }
      // B: BN=64 rows x 128 cols; wave stages rows wave*16 .. +15 (4 gll16)
      #pragma unroll
      for (int a = 0; a < 4; ++a) {
        int r0 = wave * 16 + a * 4;
        int row = r0 + rowl;
        int col = ((c16 ^ ((a * 4 + rowl) & 15)) * 8);
        gll16(WT + (size_t)(n0 + row) * K + k0 + col, &Bs[r0 * 128]);
      }
      __syncthreads();

      #pragma unroll
      for (int g = 0; g < 4; ++g) {
        bf16x8 af[4], bfr[JT];
        #pragma unroll
        for (int i = 0; i < 4; ++i)
          af[i] = *(const bf16x8*)
              &As[(wm * 64 + i * 16 + l15) * 128 + (((g * 4 + quad) ^ l15) * 8)];
        #pragma unroll
        for (int j = 0; j < JT; ++j)
          bfr[j] = *(const bf16x8*)
              &Bs[(wn * (BN / 2) + j * 16 + l15) * 128 + (((g * 4 + quad) ^ l15) * 8)];
        #pragma unroll
        for (int i = 0; i < 4; ++i)
          #pragma unroll
          for (int j = 0; j < JT; ++j)
            acc[i][j] = mfma16(af[i], bfr[j], acc[i][j]);
      }
      __syncthreads();
    }
  } else {
    // ---- BK=64 k-loop (qkv, fc1 — proven config) ------------------------
    int grow = lane >> 3;                   // 0..7
    int gcol = ((lane & 7) ^ grow) * 8;     // logical chunk for phys slot
    const bf16_t* abase = A  + (size_t)(m0 + wave * 32 + grow) * K + gcol;
    const bf16_t* bbase = WT + (size_t)(n0 + wave * (BN / 4) + grow) * K + gcol;
    int swk = l15 & 7;

    for (int k0 = k_lo; k0 < k_hi; k0 += 64) {
      #pragma unroll
      for (int a = 0; a < 4; ++a)
        gll16(abase + (size_t)a * 8 * K + k0, &As[(wave * 32 + a * 8) * 64]);
      #pragma unroll
      for (int a = 0; a < BN / 32; ++a)
        gll16(bbase + (size_t)a * 8 * K + k0, &Bs[(wave * (BN / 4) + a * 8) * 64]);
      __syncthreads();

      #pragma unroll
      for (int g = 0; g < 2; ++g) {
        bf16x8 af[4], bfr[JT];
        #pragma unroll
        for (int i = 0; i < 4; ++i)
          af[i] = *(const bf16x8*)
              &As[(wm * 64 + i * 16 + l15) * 64 + (((g * 4 + quad) ^ swk) * 8)];
        #pragma unroll
        for (int j = 0; j < JT; ++j)
          bfr[j] = *(const bf16x8*)
              &Bs[(wn * (BN / 2) + j * 16 + l15) * 64 + (((g * 4 + quad) ^ swk) * 8)];
        #pragma unroll
        for (int i = 0; i < 4; ++i)
          #pragma unroll
          for (int j = 0; j < JT; ++j)
            acc[i][j] = mfma16(af[i], bfr[j], acc[i][j]);
      }
      __syncthreads();
    }
  }

  #pragma unroll
  for (int i = 0; i < 4; ++i) {
    int mbase = m0 + wm * 64 + i * 16 + quad * 4;
    #pragma unroll
    for (int j = 0; j < JT; ++j) {
      int n = n0 + wn * (BN / 2) + j * 16 + l15;
      float bn_ = (MODE == 4 && kslice != 0) ? 0.f : bias[n];
      if (MODE == 3 && n >= 1536) {
        // V output -> vt[bh][d][l], packed 4 consecutive l per lane
        int dcol = n - 1536;
        int hh = dcol >> 6, dd = dcol & 63;
        int bsel = mbase >> 11, l = mbase & 2047;
        union { bf16_t b4[4]; uint2 u; } pk;
        #pragma unroll
        for (int r = 0; r < 4; ++r)
          pk.b4[r] = (bf16_t)(acc[i][j][r] + bn_);
        *(uint2*)&vt[(((size_t)bsel * NHEADS + hh) * HD + dd) * SEQ + l] = pk.u;
        continue;
      }
      #pragma unroll
      for (int r = 0; r < 4; ++r) {
        size_t idx = (size_t)(mbase + r) * N + n;
        float v = acc[i][j][r] + bn_;
        if (MODE == 1) {
          // tanh-GELU: v * e/(e+1), e = exp(2*0.79788456*(v+0.044715 v^3))
          float e = fast_exp2(fminf(v * (2.3020807f + 0.10293776f * v * v), 120.f));
          v = v * e * fast_rcp(e + 1.0f);
        }
        if (MODE == 3 && n < 768) v *= QSCALE;
        if (MODE == 2) {
          v += res[idx];
          ((float*)outp)[idx] = v;
        } else if (MODE == 4) {
          atomicAdd((float*)outp + idx, v);
        } else {
          ((bf16_t*)outp)[idx] = (bf16_t)v;
        }
      }
    }
  }
}

// ---------------------------------------------------------------------------
// Flash attention (R7/R8 body, measured best 43.7-45.2us — LOCKED).
// R9 (phase-batching) and R11 (deep prefetch + setprio) both regressed with
// a scratch-spill signature (WRITE_SIZE +10-18MB): the body sits exactly at
// the 84-VGPR/3-wave boundary; any restructure that widens live ranges
// spills and loses more than the schedule gains. R8's FETCH-collapse
// (53->10MB, dur flat) proved attn is NOT memory-bound; its floor is the
// per-pair issue chain at 3 waves/SIMD. Do not touch without a VGPR budget.
//   * XCD-grouped (b,h) mapping (R7): FETCH ~10MB.
//   * Pair-processed K=32 PV + ones-MFMA denominators (R3).
//   * V LDS 16B-half XOR swizzle; ring-3 wave-private bufs; guarded final
//     prefetch.
// ---------------------------------------------------------------------------
__global__ __launch_bounds__(256, 3) void attn_kernel(
    const bf16_t* __restrict__ qkv, const bf16_t* __restrict__ vt,
    bf16_t* __restrict__ attnout)
{
  // per wave: 3 bufs x (K 16x64 | V 64x16) = 12KB -> 48KB total
  __attribute__((aligned(16))) __shared__ bf16_t smem[4 * 3 * 2048];
  __shared__ float dsumf[4][64];

  // XCD-aware decode: xcd = blockIdx%8 owns bh in [xcd*3, xcd*3+3), all qt.
  int lin = blockIdx.x;
  int xcd = lin & 7;
  int idx = lin >> 3;               // 0..95
  int bh  = xcd * 3 + (idx >> 5);   // 0..23
  int qt  = idx & 31;
  int b = bh / NHEADS, h = bh % NHEADS;

  int tid = threadIdx.x;
  int wave = tid >> 6, lane = tid & 63;
  int l15 = lane & 15, quad = lane >> 4;
  int q0 = qt * 64;

  bf16_t* wbase = smem + wave * 3 * 2048;   // ring of 3: [K 1024 | V 1024]

  // Q B-frags (pre-scaled by QSCALE): n=q=l15, k=d=f*32+quad*8+j
  bf16x8 bq[4][2];
  #pragma unroll
  for (int qi = 0; qi < 4; ++qi) {
    const bf16_t* qrow = qkv + (size_t)(b * SEQ + q0 + qi * 16 + l15) * 2304
                             + h * HD + quad * 8;
    bq[qi][0] = *(const bf16x8*)qrow;
    bq[qi][1] = *(const bf16x8*)(qrow + 32);
  }
  // drain Q loads so in-loop vmcnt tracks only gll16 staging ops
  __asm__ volatile("s_waitcnt vmcnt(0)" ::: "memory");

  f32x4 accO[4][4];
  f32x4 accL[4];
  #pragma unroll
  for (int qi = 0; qi < 4; ++qi) {
    accL[qi] = (f32x4){0.f, 0.f, 0.f, 0.f};
    #pragma unroll
    for (int t2 = 0; t2 < 4; ++t2)
      accO[qi][t2] = (f32x4){0.f, 0.f, 0.f, 0.f};
  }

  // ones B-frag for denominator row-sum MFMA
  bf16x8 ones;
  #pragma unroll
  for (int r = 0; r < 8; ++r) ones[r] = (bf16_t)1.0f;

  // staging lane mappings (wave-private tiles, coalesced 16B/lane)
  int krow_l = lane >> 3;                      // 0..7
  int kchunk = ((lane & 7) ^ krow_l) * 8;      // XOR-swizzled phys chunk
  const bf16_t* ksrc0 = qkv + (size_t)(b * SEQ + wave * 16 + krow_l) * 2304
                            + 768 + h * HD + kchunk;
  int vrow_l = lane >> 1;                      // 0..31 (d rows)
  // 16B-half XOR swizzle: phys half = logical half ^ ((d>>2)&1)
  int vchunk = ((lane & 1) ^ ((vrow_l >> 2) & 1)) * 8;
  const bf16_t* vsrc0 = vt + ((size_t)bh * HD + vrow_l) * SEQ + wave * 16 + vchunk;

  constexpr int NIT = SEQ / 64;    // 32 tiles, 16 pairs

  // stage tile t into ring buffer t%3
  auto stage = [&](int t) {
    bf16_t* kb = wbase + (t % 3) * 2048;
    bf16_t* vb = kb + 1024;
    const bf16_t* ks = ksrc0 + (size_t)(t * 64) * 2304;
    const bf16_t* vs = vsrc0 + t * 64;
    #pragma unroll
    for (int p = 0; p < 2; ++p) {
      gll16(ks + (size_t)(p * 8) * 2304, kb + p * 512);
      gll16(vs + (size_t)(p * 32) * SEQ, vb + p * 512);
    }
  };

  // prologue: stage tiles 0,1
  stage(0);
  stage(1);

  // V read offset within a tile's 16-kv row (for B-frag slots j=0..3):
  // logical kv = quad*4+j -> phys = (half^((l15>>2)&1))*8 + (quad&1)*4 + j
  int vphys = (((quad >> 1) ^ ((l15 >> 2) & 1)) * 8) + (quad & 1) * 4;

  for (int p = 0; p < NIT / 2; ++p) {
    int ta = 2 * p, tb = 2 * p + 1;
    // wait for both tiles of this pair (prefetched one pair-compute ago)
    __asm__ volatile("s_waitcnt vmcnt(0)" ::: "memory");

    const bf16_t* kba = wbase + (ta % 3) * 2048;
    const bf16_t* vba = kba + 1024;
    const bf16_t* kbb = wbase + (tb % 3) * 2048;
    const bf16_t* vbb = kbb + 1024;

    // K A-frags: m=kv=l15, k=d=(f*4+quad)*8+j ; swizzle phys=c^(l15&7)
    bf16x8 aka[2], akb[2];
    #pragma unroll
    for (int f = 0; f < 2; ++f) {
      int koff = (((f * 4 + quad) ^ (l15 & 7)) * 8);
      aka[f] = *(const bf16x8*)&kba[l15 * 64 + koff];
      akb[f] = *(const bf16x8*)&kbb[l15 * 64 + koff];
    }

    // combined V B-frag (K=32): j 0..3 from tile a, 4..7 from tile b
    bf16x8 bv8[4];
    #pragma unroll
    for (int t2 = 0; t2 < 4; ++t2) {
      bf16x4 lo = *(const bf16x4*)&vba[(t2 * 16 + l15) * 16 + vphys];
      bf16x4 hi = *(const bf16x4*)&vbb[(t2 * 16 + l15) * 16 + vphys];
      bf16x8 c;
      #pragma unroll
      for (int r = 0; r < 4; ++r) { c[r] = lo[r]; c[r + 4] = hi[r]; }
      bv8[t2] = c;
    }

    // frags now issued; drain LDS reads, then overwrite-safe to prefetch
    __asm__ volatile("s_waitcnt lgkmcnt(0)" ::: "memory");
    if (p < NIT / 2 - 1) {
      stage(2 * p + 2);
      stage(2 * p + 3);
    }

    #pragma unroll
    for (int qi = 0; qi < 4; ++qi) {
      f32x4 sa = (f32x4){0.f, 0.f, 0.f, 0.f};
      sa = mfma16(aka[0], bq[qi][0], sa);   // S^T: (kv=quad*4+r, q=l15)
      sa = mfma16(aka[1], bq[qi][1], sa);
      f32x4 sb = (f32x4){0.f, 0.f, 0.f, 0.f};
      sb = mfma16(akb[0], bq[qi][0], sb);
      sb = mfma16(akb[1], bq[qi][1], sb);
      bf16x8 ap;
      #pragma unroll
      for (int r = 0; r < 4; ++r) {
        ap[r]     = (bf16_t)fast_exp2(sa[r]);
        ap[r + 4] = (bf16_t)fast_exp2(sb[r]);
      }
      // denominator row-sums on the matrix pipe
      accL[qi] = mfma16(ap, ones, accL[qi]);
      // S^T C-layout == K=32 A-frag layout of P: feed PV directly
      #pragma unroll
      for (int t2 = 0; t2 < 4; ++t2)
        accO[qi][t2] = mfma16(ap, bv8[t2], accO[qi][t2]);
    }
  }

  // publish denominators: accL C-layout: row q_sub=quad*4+r, col l15 (equal
  // across l15) -> lanes with l15==0 write 4 rows each
  if (l15 == 0) {
    #pragma unroll
    for (int qi = 0; qi < 4; ++qi)
      #pragma unroll
      for (int r = 0; r < 4; ++r)
        dsumf[wave][qi * 16 + quad * 4 + r] = accL[qi][r];
  }
  __syncthreads();   // waves done with private tiles; dsumf published

  float* slabf = (float*)smem;   // 4 slabs x 2048 f32 = 32 KB (ring region)

  for (int pass = 0; pass < 2; ++pass) {
    #pragma unroll
    for (int qi2 = 0; qi2 < 2; ++qi2) {
      int qi = pass * 2 + qi2;
      #pragma unroll
      for (int t2 = 0; t2 < 4; ++t2)
        #pragma unroll
        for (int r = 0; r < 4; ++r)
          slabf[wave * 2048 + (qi2 * 16 + quad * 4 + r) * 64 + t2 * 16 + l15]
              = accO[qi][t2][r];
    }
    __syncthreads();
    int row = tid >> 3;            // 0..31
    int d0 = (tid & 7) * 8;
    f32x4 o0 = (f32x4){0.f,0.f,0.f,0.f}, o1 = (f32x4){0.f,0.f,0.f,0.f};
    #pragma unroll
    for (int sw = 0; sw < 4; ++sw) {
      o0 += *(const f32x4*)&slabf[sw * 2048 + row * 64 + d0];
      o1 += *(const f32x4*)&slabf[sw * 2048 + row * 64 + d0 + 4];
    }
    int q_abs = pass * 32 + row;
    float den = dsumf[0][q_abs] + dsumf[1][q_abs] + dsumf[2][q_abs] + dsumf[3][q_abs];
    float inv = 1.0f / den;
    bf16_t ob[8];
    #pragma unroll
    for (int j = 0; j < 4; ++j) {
      ob[j]     = (bf16_t)(o0[j] * inv);
      ob[j + 4] = (bf16_t)(o1[j] * inv);
    }
    *(uint4*)&attnout[(size_t)(b * SEQ + q0 + q_abs) * EMBED + h * HD + d0]
        = *(const uint4*)ob;
    if (pass == 0) __syncthreads();
  }
}

// ---------------------------------------------------------------------------
extern "C" void kernel_launch(void* const* d_in, const int* in_sizes, int n_in,
                              void* d_out, int out_size, void* d_ws, size_t ws_size,
                              hipStream_t stream) {
  (void)in_sizes; (void)n_in; (void)out_size; (void)ws_size;
  const float* x      = (const float*)d_in[0];
  const float* ln1_g  = (const float*)d_in[1];
  const float* ln1_b  = (const float*)d_in[2];
  const float* qkv_w  = (const float*)d_in[3];
  const float* qkv_b  = (const float*)d_in[4];
  const float* proj_w = (const float*)d_in[5];
  const float* proj_b = (const float*)d_in[6];
  const float* ln2_g  = (const float*)d_in[7];
  const float* ln2_b  = (const float*)d_in[8];
  const float* fc1_w  = (const float*)d_in[9];
  const float* fc1_b  = (const float*)d_in[10];
  const float* fc2_w  = (const float*)d_in[11];
  const float* fc2_b  = (const float*)d_in[12];
  float* out = (float*)d_out;

  char* p = (char*)d_ws;
  bf16_t* wqkvT  = (bf16_t*)p; p += (size_t)2304 * 768 * 2;
  bf16_t* wprojT = (bf16_t*)p; p += (size_t)768 * 768 * 2;
  bf16_t* wfc1T  = (bf16_t*)p; p += (size_t)3072 * 768 * 2;
  bf16_t* wfc2T  = (bf16_t*)p; p += (size_t)768 * 3072 * 2;
  bf16_t* hbuf   = (bf16_t*)p; p += (size_t)ROWS * 768 * 2;
  bf16_t* qkv    = (bf16_t*)p;          // dead after attention
  bf16_t* hid    = (bf16_t*)p; p += (size_t)ROWS * 3072 * 2;  // aliases qkv
  bf16_t* vt     = (bf16_t*)p; p += (size_t)BATCH * NHEADS * HD * SEQ * 2;
  bf16_t* attno  = (bf16_t*)p; p += (size_t)ROWS * 768 * 2;

  // weight prep + LN1 (one launch; no static state allowed)
  prep_kernel<<<6912 + ROWS, 256, 0, stream>>>(
      qkv_w, wqkvT, proj_w, wprojT, fc1_w, wfc1T, fc2_w, wfc2T,
      x, ln1_g, ln1_b, hbuf);

  // attention sublayer (qkv GEMM writes V directly transposed into vt)
  gemm_kernel<3,128><<<32 * (2304/128), 256, 0, stream>>>(
      hbuf, wqkvT, qkv_b, nullptr, qkv, vt, 2304, 768);
  attn_kernel<<<768, 256, 0, stream>>>(qkv, vt, attno);
  gemm_kernel<2,64><<<32 * (768/64), 256, 0, stream>>>(
      attno, wprojT, proj_b, x, out, nullptr, 768, 768);

  // FFN sublayer
  ln_kernel<<<ROWS, 256, 0, stream>>>(out, ln2_g, ln2_b, hbuf);
  gemm_kernel<1,128><<<32 * (3072/128), 256, 0, stream>>>(
      hbuf, wfc1T, fc1_b, nullptr, hid, nullptr, 3072, 768);
  gemm_kernel<4,64,2><<<2 * 32 * (768/64), 256, 0, stream>>>(
      hid, wfc2T, fc2_b, nullptr, out, nullptr, 768, 3072);
}